// Round 5
// baseline (2555.508 us; speedup 1.0000x reference)
//
#include <hip/hip_runtime.h>

typedef unsigned long long u64;
typedef unsigned int u32;
typedef float v2f __attribute__((ext_vector_type(2)));

#define NB   8
#define NPC  8192
#define SS   2048
#define KK   32
#define CIN  64
#define NQ   (NB*SS)              // 16384
#define POS_OUT_OFF   (NQ*128)
#define BATCH_OUT_OFF (NQ*128 + NQ*3)
#define INF64 0x7ff0000000000000ULL

// Packed f32 ops via inline asm: IEEE round-to-nearest-even, bit-identical to
// scalar v_add_f32/v_mul_f32 per half; immune to -ffp-contract fusing.
__device__ __forceinline__ v2f pk_add(v2f a, v2f b) {
    v2f r; asm("v_pk_add_f32 %0, %1, %2" : "=v"(r) : "v"(a), "v"(b)); return r;
}
__device__ __forceinline__ v2f pk_mul(v2f a, v2f b) {
    v2f r; asm("v_pk_mul_f32 %0, %1, %2" : "=v"(r) : "v"(a), "v"(b)); return r;
}

// ---- wave64 reductions via DPP (VALU latency; gfx9 row_bcast sequence) ----
// row_shr:1/2/4/8 then row_bcast:15, row_bcast:31 -> lane 63 holds the result.
// old = own value, bound_ctrl=false: invalid lanes yield identity for max/min.
__device__ __forceinline__ float dpp_wave_max_f32(float v) {
    int x = __float_as_int(v), t;
    t = __builtin_amdgcn_update_dpp(x, x, 0x111, 0xf, 0xf, false);
    v = fmaxf(v, __int_as_float(t)); x = __float_as_int(v);
    t = __builtin_amdgcn_update_dpp(x, x, 0x112, 0xf, 0xf, false);
    v = fmaxf(v, __int_as_float(t)); x = __float_as_int(v);
    t = __builtin_amdgcn_update_dpp(x, x, 0x114, 0xf, 0xf, false);
    v = fmaxf(v, __int_as_float(t)); x = __float_as_int(v);
    t = __builtin_amdgcn_update_dpp(x, x, 0x118, 0xf, 0xf, false);
    v = fmaxf(v, __int_as_float(t)); x = __float_as_int(v);
    t = __builtin_amdgcn_update_dpp(x, x, 0x142, 0xf, 0xf, false);   // row_bcast:15
    v = fmaxf(v, __int_as_float(t)); x = __float_as_int(v);
    t = __builtin_amdgcn_update_dpp(x, x, 0x143, 0xf, 0xf, false);   // row_bcast:31
    v = fmaxf(v, __int_as_float(t));
    return v;                       // valid in lane 63
}
__device__ __forceinline__ u32 dpp_wave_min_u32(u32 v) {
    int x = (int)v, t;
    t = __builtin_amdgcn_update_dpp(x, x, 0x111, 0xf, 0xf, false);
    v = ((u32)t < v) ? (u32)t : v; x = (int)v;
    t = __builtin_amdgcn_update_dpp(x, x, 0x112, 0xf, 0xf, false);
    v = ((u32)t < v) ? (u32)t : v; x = (int)v;
    t = __builtin_amdgcn_update_dpp(x, x, 0x114, 0xf, 0xf, false);
    v = ((u32)t < v) ? (u32)t : v; x = (int)v;
    t = __builtin_amdgcn_update_dpp(x, x, 0x118, 0xf, 0xf, false);
    v = ((u32)t < v) ? (u32)t : v; x = (int)v;
    t = __builtin_amdgcn_update_dpp(x, x, 0x142, 0xf, 0xf, false);
    v = ((u32)t < v) ? (u32)t : v; x = (int)v;
    t = __builtin_amdgcn_update_dpp(x, x, 0x143, 0xf, 0xf, false);
    v = ((u32)t < v) ? (u32)t : v;
    return v;                       // valid in lane 63
}

// ---------------- Kernel 1: exact farthest point sampling -------------------
// One block/cloud, 512 thr x 16 pts. Two-phase 32-bit reduce:
//   (1) M = block max of mind (f32 DPP wave reduce + 8 LDS partials)
//   (2) widx = min original index with mind == M (u32 DPP reduce)
// Exactly matches jnp.argmax first-max-index semantics.
__global__ __launch_bounds__(512) void fps_kernel(const float* __restrict__ pos,
                                                  float* __restrict__ out)
{
    __shared__ float lp[NPC*3];
    __shared__ float redM[8];
    __shared__ u32   redI[8];
    __shared__ unsigned short hist[SS];
    const int tid  = threadIdx.x;
    const int wid  = tid >> 6;
    const int lane = tid & 63;
    const int cloud = blockIdx.x;
    const float* cp = pos + (size_t)cloud * (NPC*3);

    {   // stage cloud positions into LDS (coalesced float4)
        const float4* s4 = (const float4*)cp;
        float4* d4 = (float4*)lp;
        #pragma unroll
        for (int i = 0; i < 12; ++i) d4[tid + i*512] = s4[tid + i*512];
    }
    __syncthreads();

    v2f px[8], py[8], pz[8], mind[8];
    const float finf = __int_as_float(0x7f800000);
    #pragma unroll
    for (int k = 0; k < 8; ++k) {
        int j = tid*16 + 2*k;
        px[k] = (v2f){lp[j*3+0], lp[j*3+3]};
        py[k] = (v2f){lp[j*3+1], lp[j*3+4]};
        pz[k] = (v2f){lp[j*3+2], lp[j*3+5]};
        mind[k] = (v2f){finf, finf};
    }

    float cx = lp[0], cy = lp[1], cz = lp[2];
    u32 widx = 0;

    for (int s = 0; s < SS; ++s) {
        if (tid == 0) hist[s] = (unsigned short)widx;
        // p + (-c) rounds identically to p - c (exact sign flip on c)
        v2f ncx = (v2f){-cx,-cx}, ncy = (v2f){-cy,-cy}, ncz = (v2f){-cz,-cz};
        #pragma unroll
        for (int k = 0; k < 8; ++k) {
            v2f dx = pk_add(px[k], ncx);
            v2f dy = pk_add(py[k], ncy);
            v2f dz = pk_add(pz[k], ncz);
            v2f d  = pk_add(pk_add(pk_mul(dx,dx), pk_mul(dy,dy)), pk_mul(dz,dz));
            mind[k].x = fminf(mind[k].x, d.x);
            mind[k].y = fminf(mind[k].y, d.y);
        }
        // ---- phase 1: block max of mind ----
        float a[8];
        #pragma unroll
        for (int k = 0; k < 8; ++k) a[k] = fmaxf(mind[k].x, mind[k].y);
        #pragma unroll
        for (int st = 4; st >= 1; st >>= 1) {
            #pragma unroll
            for (int k = 0; k < st; ++k) a[k] = fmaxf(a[k], a[k+st]);
        }
        float wm = dpp_wave_max_f32(a[0]);
        if (lane == 63) redM[wid] = wm;
        __syncthreads();                         // B1
        float M = fmaxf(fmaxf(fmaxf(redM[0],redM[1]), fmaxf(redM[2],redM[3])),
                        fmaxf(fmaxf(redM[4],redM[5]), fmaxf(redM[6],redM[7])));
        // ---- phase 2: lowest original index with mind == M ----
        u32 cand = 0xFFFFFFFFu;
        #pragma unroll
        for (int k = 15; k >= 0; --k) {
            float mv = (k & 1) ? mind[k>>1].y : mind[k>>1].x;
            cand = (mv == M) ? (u32)(tid*16 + k) : cand;
        }
        cand = dpp_wave_min_u32(cand);
        if (lane == 63) redI[wid] = cand;
        __syncthreads();                         // B2
        u32 g0 = redI[0] < redI[1] ? redI[0] : redI[1];
        u32 g1 = redI[2] < redI[3] ? redI[2] : redI[3];
        u32 g2 = redI[4] < redI[5] ? redI[4] : redI[5];
        u32 g3 = redI[6] < redI[7] ? redI[6] : redI[7];
        g0 = g0 < g1 ? g0 : g1;  g2 = g2 < g3 ? g2 : g3;
        widx = g0 < g2 ? g0 : g2;
        cx = lp[widx*3+0]; cy = lp[widx*3+1]; cz = lp[widx*3+2];
    }
    __syncthreads();

    float* qout = out + POS_OUT_OFF   + (size_t)cloud * SS * 3;
    float* bout = out + BATCH_OUT_OFF + (size_t)cloud * SS;
    for (int s = tid; s < SS; s += 512) {
        u32 w = hist[s];
        qout[s*3+0] = lp[w*3+0];
        qout[s*3+1] = lp[w*3+1];
        qout[s*3+2] = lp[w*3+2];
        bout[s] = (float)cloud;
    }
}

// ---------------- Kernel 2: radius / 32 smallest-d2 selection ---------------
// Global-direct scan (cloud is L2-resident across the 64 blocks sharing it),
// ballot-compacted candidates in LDS, f64-key min extraction.
#define CAND_MAX 640
__global__ __launch_bounds__(256) void radius_kernel(const float* __restrict__ pos,
                                                     const float* __restrict__ out,
                                                     int* __restrict__ nidx,
                                                     int* __restrict__ ncnt)
{
    __shared__ u64 cand[4][CAND_MAX];
    const int tid  = threadIdx.x;
    const int wid  = tid >> 6;
    const int lane = tid & 63;
    const float R2 = (float)(0.2 * 0.2);        // float32(0.04) = 0x3D23D70A
    const float* qpos = out + POS_OUT_OFF;
    u64* cw = cand[wid];

    for (int qq = 0; qq < 4; ++qq) {
        const int q     = blockIdx.x*16 + wid*4 + qq;
        const int cloud = q >> 11;
        const float* cp = pos + (size_t)cloud * (NPC*3);
        float qx = qpos[q*3+0], qy = qpos[q*3+1], qz = qpos[q*3+2];

        int m = 0;
        for (int c = 0; c < NPC/64; ++c) {
            int j = c*64 + lane;
            float dx = __fsub_rn(cp[j*3+0], qx);
            float dy = __fsub_rn(cp[j*3+1], qy);
            float dz = __fsub_rn(cp[j*3+2], qz);
            float d2 = __fadd_rn(__fadd_rn(__fmul_rn(dx,dx), __fmul_rn(dy,dy)), __fmul_rn(dz,dz));
            bool in = (d2 <= R2);
            u64 mk = __ballot(in);
            if (in) {
                int p = m + __popcll(mk & ((1ull << lane) - 1ull));
                if (p < CAND_MAX) cw[p] = ((u64)__float_as_uint(d2) << 32) | (u32)j;
            }
            m += __popcll(mk);
        }
        if (m > CAND_MAX) m = CAND_MAX;

        double kk[10];
        #pragma unroll
        for (int t = 0; t < 10; ++t) {
            int p = t*64 + lane;
            kk[t] = (p < m) ? __longlong_as_double((long long)cw[p])
                            : __longlong_as_double((long long)INF64);
        }
        int cq = (m < KK) ? m : KK;
        int* nq = nidx + (size_t)q * KK;
        int j0 = 0;
        #pragma unroll 1
        for (int r = 0; r < KK; ++r) {
            double lmin = kk[0];
            #pragma unroll
            for (int t = 1; t < 10; ++t) lmin = fmin(lmin, kk[t]);
            #pragma unroll
            for (int off = 32; off >= 1; off >>= 1)
                lmin = fmin(lmin, __shfl_xor(lmin, off));
            u64 lb = (u64)__double_as_longlong(lmin);
            int j = (int)(u32)lb;
            if (r == 0) j0 = j;                 // center itself (d2=0) is first
            if (lane == 0) nq[r] = (lb == INF64) ? j0 : j;
            #pragma unroll
            for (int t = 0; t < 10; ++t)
                if ((u64)__double_as_longlong(kk[t]) == lb)
                    kk[t] = __longlong_as_double((long long)INF64);
        }
        if (lane == 0) ncnt[q] = cq;
    }
}

// ---------------- Kernel 3: gather + 3-layer MLP + masked max ---------------
// Weights/biases read straight from global with wave-uniform indices ->
// compiler emits s_load broadcasts (no LDS pipe pressure). feat in padded LDS.
__global__ __launch_bounds__(256) void mlp_kernel(const float* __restrict__ x,
                                                  const float* __restrict__ pos,
                                                  const float* __restrict__ W1, const float* __restrict__ b1,
                                                  const float* __restrict__ W2, const float* __restrict__ b2,
                                                  const float* __restrict__ W3, const float* __restrict__ b3,
                                                  const int* __restrict__ nidx, const int* __restrict__ ncnt,
                                                  float* __restrict__ out)
{
    __shared__ float flds[256*69];

    const int tid   = threadIdx.x;
    const int q     = blockIdx.x * 8 + (tid >> 5);
    const int slot  = tid & 31;
    const int cloud = q >> 11;
    const int j     = nidx[q*KK + slot];
    const bool valid = slot < ncnt[q];
    const size_t row = (size_t)cloud * NPC + (size_t)j;

    const float* qp = out + POS_OUT_OFF + (size_t)q*3;
    float qx = qp[0], qy = qp[1], qz = qp[2];

    float* myf = &flds[tid*69];
    {
        const float4* xr = (const float4*)(x + row*CIN);
        #pragma unroll
        for (int i = 0; i < 16; ++i) {
            float4 v = xr[i];
            myf[i*4+0]=v.x; myf[i*4+1]=v.y; myf[i*4+2]=v.z; myf[i*4+3]=v.w;
        }
        myf[64] = __fsub_rn(pos[row*3+0], qx);
        myf[65] = __fsub_rn(pos[row*3+1], qy);
        myf[66] = __fsub_rn(pos[row*3+2], qz);
    }
    // each thread reads only its own flds region: no barrier needed

    float acc[64];
    // ----- layer 1: 67 -> 64, relu -----
    #pragma unroll
    for (int o = 0; o < 64; ++o) acc[o] = b1[o];
    #pragma unroll 2
    for (int i = 0; i < 67; ++i) {
        float f = myf[i];
        const float4* wr = (const float4*)(W1 + i*64);
        #pragma unroll
        for (int o4 = 0; o4 < 16; ++o4) {
            float4 wv = wr[o4];
            acc[o4*4+0] = fmaf(f, wv.x, acc[o4*4+0]);
            acc[o4*4+1] = fmaf(f, wv.y, acc[o4*4+1]);
            acc[o4*4+2] = fmaf(f, wv.z, acc[o4*4+2]);
            acc[o4*4+3] = fmaf(f, wv.w, acc[o4*4+3]);
        }
    }
    #pragma unroll
    for (int o = 0; o < 64; ++o) myf[o] = fmaxf(acc[o], 0.0f);

    // ----- layer 2: 64 -> 64, relu -----
    #pragma unroll
    for (int o = 0; o < 64; ++o) acc[o] = b2[o];
    #pragma unroll 2
    for (int i = 0; i < 64; ++i) {
        float f = myf[i];
        const float4* wr = (const float4*)(W2 + i*64);
        #pragma unroll
        for (int o4 = 0; o4 < 16; ++o4) {
            float4 wv = wr[o4];
            acc[o4*4+0] = fmaf(f, wv.x, acc[o4*4+0]);
            acc[o4*4+1] = fmaf(f, wv.y, acc[o4*4+1]);
            acc[o4*4+2] = fmaf(f, wv.z, acc[o4*4+2]);
            acc[o4*4+3] = fmaf(f, wv.w, acc[o4*4+3]);
        }
    }
    #pragma unroll
    for (int o = 0; o < 64; ++o) myf[o] = fmaxf(acc[o], 0.0f);

    // ----- layer 3: 64 -> 128 (two halves), mask, max over 32 slots -----
    float* orow = out + (size_t)q*128;
    const float NEGINF = __int_as_float(0xff800000);
    for (int h = 0; h < 2; ++h) {
        #pragma unroll
        for (int o = 0; o < 64; ++o) acc[o] = b3[h*64 + o];
        const float* w3h = W3 + h*64;
        #pragma unroll 2
        for (int i = 0; i < 64; ++i) {
            float f = myf[i];
            const float4* wr = (const float4*)(w3h + i*128);
            #pragma unroll
            for (int o4 = 0; o4 < 16; ++o4) {
                float4 wv = wr[o4];
                acc[o4*4+0] = fmaf(f, wv.x, acc[o4*4+0]);
                acc[o4*4+1] = fmaf(f, wv.y, acc[o4*4+1]);
                acc[o4*4+2] = fmaf(f, wv.z, acc[o4*4+2]);
                acc[o4*4+3] = fmaf(f, wv.w, acc[o4*4+3]);
            }
        }
        #pragma unroll
        for (int o = 0; o < 64; ++o) if (!valid) acc[o] = NEGINF;
        #pragma unroll
        for (int off = 16; off >= 1; off >>= 1) {
            #pragma unroll
            for (int o = 0; o < 64; ++o) acc[o] = fmaxf(acc[o], __shfl_xor(acc[o], off));
        }
        if (slot == 0) {
            #pragma unroll
            for (int o = 0; o < 64; o += 4) {
                float4 v = make_float4(acc[o], acc[o+1], acc[o+2], acc[o+3]);
                *(float4*)&orow[h*64+o] = v;
            }
        }
    }
}

// ------------------------------- launcher -----------------------------------
extern "C" void kernel_launch(void* const* d_in, const int* in_sizes, int n_in,
                              void* d_out, int out_size, void* d_ws, size_t ws_size,
                              hipStream_t stream) {
    const float* x   = (const float*)d_in[0];
    const float* pos = (const float*)d_in[1];
    // d_in[2]=batch (implicit), d_in[3]=num_samples (K=32 hardcoded)
    const float* W1 = (const float*)d_in[4];
    const float* b1 = (const float*)d_in[5];
    const float* W2 = (const float*)d_in[6];
    const float* b2 = (const float*)d_in[7];
    const float* W3 = (const float*)d_in[8];
    const float* b3 = (const float*)d_in[9];
    float* out = (float*)d_out;

    int* nidx = (int*)d_ws;                  // NQ*KK ints (2 MiB)
    int* ncnt = nidx + (size_t)NQ*KK;        // NQ ints

    hipLaunchKernelGGL(fps_kernel,    dim3(NB),      dim3(512), 0, stream, pos, out);
    hipLaunchKernelGGL(radius_kernel, dim3(NQ/16),   dim3(256), 0, stream, pos, out, nidx, ncnt);
    hipLaunchKernelGGL(mlp_kernel,    dim3(NQ/8),    dim3(256), 0, stream,
                       x, pos, W1, b1, W2, b2, W3, b3, nidx, ncnt, out);
}

// Round 6
// 2103.904 us; speedup vs baseline: 1.2147x; 1.2147x over previous
//
#include <hip/hip_runtime.h>

typedef unsigned long long u64;
typedef unsigned int u32;
typedef float v2f __attribute__((ext_vector_type(2)));

#define NB   8
#define NPC  8192
#define SS   2048
#define KK   32
#define CIN  64
#define NQ   (NB*SS)              // 16384
#define POS_OUT_OFF   (NQ*128)
#define BATCH_OUT_OFF (NQ*128 + NQ*3)
#define INF64 0x7ff0000000000000ULL

// Packed f32 ops via inline asm: IEEE round-to-nearest-even, bit-identical to
// scalar v_add_f32/v_mul_f32 per half; immune to -ffp-contract fusing.
__device__ __forceinline__ v2f pk_add(v2f a, v2f b) {
    v2f r; asm("v_pk_add_f32 %0, %1, %2" : "=v"(r) : "v"(a), "v"(b)); return r;
}
__device__ __forceinline__ v2f pk_mul(v2f a, v2f b) {
    v2f r; asm("v_pk_mul_f32 %0, %1, %2" : "=v"(r) : "v"(a), "v"(b)); return r;
}
// key = (mind_bits<<32) | ~idx, viewed as f64. mind_bits <= 0x7f800000 so the
// f64 exponent field < 2047: never NaN -> fmax == exact u64 max (positive).
__device__ __forceinline__ double mkkey(float m, u32 ni) {
    return __hiloint2double((int)__float_as_uint(m), (int)ni);
}
// 64-bit wave max via paired 32-bit DPP moves (same ctrl -> coherent pairs;
// bound_ctrl=false keeps own value on boundary lanes = identity for max).
// gfx9 sequence row_shr:1/2/4/8, row_bcast:15, row_bcast:31 -> lane 63 valid.
__device__ __forceinline__ double dpp_wave_max_key(double v) {
#define DPP_LVL(ctrl) { \
    int lo = __double2loint(v), hi = __double2hiint(v); \
    int tlo = __builtin_amdgcn_update_dpp(lo, lo, ctrl, 0xf, 0xf, false); \
    int thi = __builtin_amdgcn_update_dpp(hi, hi, ctrl, 0xf, 0xf, false); \
    v = fmax(v, __hiloint2double(thi, tlo)); }
    DPP_LVL(0x111) DPP_LVL(0x112) DPP_LVL(0x114) DPP_LVL(0x118)
    DPP_LVL(0x142) DPP_LVL(0x143)
#undef DPP_LVL
    return v;                       // valid in lane 63
}

// ---------------- Kernel 1: exact farthest point sampling -------------------
// One block/cloud, 256 thr (4 waves = 1/SIMD) x 32 pts. Single barrier/step:
// per-thread f64-key fold -> paired-DPP wave max -> 4 LDS partials -> combine.
__global__ __launch_bounds__(256) void fps_kernel(const float* __restrict__ pos,
                                                  float* __restrict__ out)
{
    __shared__ float lp[NPC*3];
    __shared__ double red[2][4];
    __shared__ unsigned short hist[SS];
    const int tid  = threadIdx.x;
    const int wid  = tid >> 6;
    const int lane = tid & 63;
    const int cloud = blockIdx.x;
    const float* cp = pos + (size_t)cloud * (NPC*3);

    {   // stage cloud positions into LDS (coalesced float4)
        const float4* s4 = (const float4*)cp;
        float4* d4 = (float4*)lp;
        #pragma unroll
        for (int i = 0; i < 24; ++i) d4[tid + i*256] = s4[tid + i*256];
    }
    __syncthreads();

    v2f px[16], py[16], pz[16], mind[16];
    u32 inv[32];
    const float finf = __int_as_float(0x7f800000);
    #pragma unroll
    for (int k = 0; k < 16; ++k) {
        int j = tid*32 + 2*k;
        px[k] = (v2f){lp[j*3+0], lp[j*3+3]};
        py[k] = (v2f){lp[j*3+1], lp[j*3+4]};
        pz[k] = (v2f){lp[j*3+2], lp[j*3+5]};
        mind[k] = (v2f){finf, finf};
    }
    #pragma unroll
    for (int k = 0; k < 32; ++k) inv[k] = ~(u32)(tid*32 + k);

    float cx = lp[0], cy = lp[1], cz = lp[2];
    u32 widx = 0;

    for (int s = 0; s < SS; ++s) {
        if (tid == 0) hist[s] = (unsigned short)widx;
        // p + (-c) rounds identically to p - c (exact sign flip on c)
        v2f ncx = (v2f){-cx,-cx}, ncy = (v2f){-cy,-cy}, ncz = (v2f){-cz,-cz};
        double kd[8];
        #pragma unroll
        for (int k = 0; k < 16; ++k) {
            v2f dx = pk_add(px[k], ncx);
            v2f dy = pk_add(py[k], ncy);
            v2f dz = pk_add(pz[k], ncz);
            v2f d  = pk_add(pk_add(pk_mul(dx,dx), pk_mul(dy,dy)), pk_mul(dz,dz));
            float m0 = fminf(mind[k].x, d.x);
            float m1 = fminf(mind[k].y, d.y);
            mind[k].x = m0; mind[k].y = m1;
            double ab = fmax(mkkey(m0, inv[2*k]), mkkey(m1, inv[2*k+1]));
            kd[k & 7] = (k < 8) ? ab : fmax(kd[k & 7], ab);
        }
        #pragma unroll
        for (int st = 4; st >= 1; st >>= 1) {
            #pragma unroll
            for (int k = 0; k < st; ++k) kd[k] = fmax(kd[k], kd[k+st]);
        }
        double wk = dpp_wave_max_key(kd[0]);
        if (lane == 63) red[s&1][wid] = wk;
        __syncthreads();                          // single barrier per step
        const double* rb = red[s&1];
        double g = fmax(fmax(rb[0], rb[1]), fmax(rb[2], rb[3]));
        widx = ~(u32)__double2loint(g);
        cx = lp[widx*3+0]; cy = lp[widx*3+1]; cz = lp[widx*3+2];
    }
    __syncthreads();

    float* qout = out + POS_OUT_OFF   + (size_t)cloud * SS * 3;
    float* bout = out + BATCH_OUT_OFF + (size_t)cloud * SS;
    for (int s = tid; s < SS; s += 256) {
        u32 w = hist[s];
        qout[s*3+0] = lp[w*3+0];
        qout[s*3+1] = lp[w*3+1];
        qout[s*3+2] = lp[w*3+2];
        bout[s] = (float)cloud;
    }
}

// ---------------- Kernel 2: radius / 32 smallest-d2 selection ---------------
// Global-direct scan (cloud is L2-resident across the 64 blocks sharing it),
// ballot-compacted candidates in LDS, f64-key min extraction.
#define CAND_MAX 640
__global__ __launch_bounds__(256) void radius_kernel(const float* __restrict__ pos,
                                                     const float* __restrict__ out,
                                                     int* __restrict__ nidx,
                                                     int* __restrict__ ncnt)
{
    __shared__ u64 cand[4][CAND_MAX];
    const int tid  = threadIdx.x;
    const int wid  = tid >> 6;
    const int lane = tid & 63;
    const float R2 = (float)(0.2 * 0.2);        // float32(0.04) = 0x3D23D70A
    const float* qpos = out + POS_OUT_OFF;
    u64* cw = cand[wid];

    for (int qq = 0; qq < 4; ++qq) {
        const int q     = blockIdx.x*16 + wid*4 + qq;
        const int cloud = q >> 11;
        const float* cp = pos + (size_t)cloud * (NPC*3);
        float qx = qpos[q*3+0], qy = qpos[q*3+1], qz = qpos[q*3+2];

        int m = 0;
        for (int c = 0; c < NPC/64; ++c) {
            int j = c*64 + lane;
            float dx = __fsub_rn(cp[j*3+0], qx);
            float dy = __fsub_rn(cp[j*3+1], qy);
            float dz = __fsub_rn(cp[j*3+2], qz);
            float d2 = __fadd_rn(__fadd_rn(__fmul_rn(dx,dx), __fmul_rn(dy,dy)), __fmul_rn(dz,dz));
            bool in = (d2 <= R2);
            u64 mk = __ballot(in);
            if (in) {
                int p = m + __popcll(mk & ((1ull << lane) - 1ull));
                if (p < CAND_MAX) cw[p] = ((u64)__float_as_uint(d2) << 32) | (u32)j;
            }
            m += __popcll(mk);
        }
        if (m > CAND_MAX) m = CAND_MAX;

        double kk[10];
        #pragma unroll
        for (int t = 0; t < 10; ++t) {
            int p = t*64 + lane;
            kk[t] = (p < m) ? __longlong_as_double((long long)cw[p])
                            : __longlong_as_double((long long)INF64);
        }
        int cq = (m < KK) ? m : KK;
        int* nq = nidx + (size_t)q * KK;
        int j0 = 0;
        #pragma unroll 1
        for (int r = 0; r < KK; ++r) {
            double lmin = kk[0];
            #pragma unroll
            for (int t = 1; t < 10; ++t) lmin = fmin(lmin, kk[t]);
            #pragma unroll
            for (int off = 32; off >= 1; off >>= 1)
                lmin = fmin(lmin, __shfl_xor(lmin, off));
            u64 lb = (u64)__double_as_longlong(lmin);
            int j = (int)(u32)lb;
            if (r == 0) j0 = j;                 // center itself (d2=0) is first
            if (lane == 0) nq[r] = (lb == INF64) ? j0 : j;
            #pragma unroll
            for (int t = 0; t < 10; ++t)
                if ((u64)__double_as_longlong(kk[t]) == lb)
                    kk[t] = __longlong_as_double((long long)INF64);
        }
        if (lane == 0) ncnt[q] = cq;
    }
}

// ---------------- Kernel 3: gather + 3-layer MLP + masked max ---------------
// Weights/biases read straight from global with wave-uniform indices ->
// compiler emits s_load broadcasts (no LDS pipe pressure). feat in padded LDS.
__global__ __launch_bounds__(256) void mlp_kernel(const float* __restrict__ x,
                                                  const float* __restrict__ pos,
                                                  const float* __restrict__ W1, const float* __restrict__ b1,
                                                  const float* __restrict__ W2, const float* __restrict__ b2,
                                                  const float* __restrict__ W3, const float* __restrict__ b3,
                                                  const int* __restrict__ nidx, const int* __restrict__ ncnt,
                                                  float* __restrict__ out)
{
    __shared__ float flds[256*69];

    const int tid   = threadIdx.x;
    const int q     = blockIdx.x * 8 + (tid >> 5);
    const int slot  = tid & 31;
    const int cloud = q >> 11;
    const int j     = nidx[q*KK + slot];
    const bool valid = slot < ncnt[q];
    const size_t row = (size_t)cloud * NPC + (size_t)j;

    const float* qp = out + POS_OUT_OFF + (size_t)q*3;
    float qx = qp[0], qy = qp[1], qz = qp[2];

    float* myf = &flds[tid*69];
    {
        const float4* xr = (const float4*)(x + row*CIN);
        #pragma unroll
        for (int i = 0; i < 16; ++i) {
            float4 v = xr[i];
            myf[i*4+0]=v.x; myf[i*4+1]=v.y; myf[i*4+2]=v.z; myf[i*4+3]=v.w;
        }
        myf[64] = __fsub_rn(pos[row*3+0], qx);
        myf[65] = __fsub_rn(pos[row*3+1], qy);
        myf[66] = __fsub_rn(pos[row*3+2], qz);
    }
    // each thread reads only its own flds region: no barrier needed

    float acc[64];
    // ----- layer 1: 67 -> 64, relu -----
    #pragma unroll
    for (int o = 0; o < 64; ++o) acc[o] = b1[o];
    #pragma unroll 2
    for (int i = 0; i < 67; ++i) {
        float f = myf[i];
        const float4* wr = (const float4*)(W1 + i*64);
        #pragma unroll
        for (int o4 = 0; o4 < 16; ++o4) {
            float4 wv = wr[o4];
            acc[o4*4+0] = fmaf(f, wv.x, acc[o4*4+0]);
            acc[o4*4+1] = fmaf(f, wv.y, acc[o4*4+1]);
            acc[o4*4+2] = fmaf(f, wv.z, acc[o4*4+2]);
            acc[o4*4+3] = fmaf(f, wv.w, acc[o4*4+3]);
        }
    }
    #pragma unroll
    for (int o = 0; o < 64; ++o) myf[o] = fmaxf(acc[o], 0.0f);

    // ----- layer 2: 64 -> 64, relu -----
    #pragma unroll
    for (int o = 0; o < 64; ++o) acc[o] = b2[o];
    #pragma unroll 2
    for (int i = 0; i < 64; ++i) {
        float f = myf[i];
        const float4* wr = (const float4*)(W2 + i*64);
        #pragma unroll
        for (int o4 = 0; o4 < 16; ++o4) {
            float4 wv = wr[o4];
            acc[o4*4+0] = fmaf(f, wv.x, acc[o4*4+0]);
            acc[o4*4+1] = fmaf(f, wv.y, acc[o4*4+1]);
            acc[o4*4+2] = fmaf(f, wv.z, acc[o4*4+2]);
            acc[o4*4+3] = fmaf(f, wv.w, acc[o4*4+3]);
        }
    }
    #pragma unroll
    for (int o = 0; o < 64; ++o) myf[o] = fmaxf(acc[o], 0.0f);

    // ----- layer 3: 64 -> 128 (two halves), mask, max over 32 slots -----
    float* orow = out + (size_t)q*128;
    const float NEGINF = __int_as_float(0xff800000);
    for (int h = 0; h < 2; ++h) {
        #pragma unroll
        for (int o = 0; o < 64; ++o) acc[o] = b3[h*64 + o];
        const float* w3h = W3 + h*64;
        #pragma unroll 2
        for (int i = 0; i < 64; ++i) {
            float f = myf[i];
            const float4* wr = (const float4*)(w3h + i*128);
            #pragma unroll
            for (int o4 = 0; o4 < 16; ++o4) {
                float4 wv = wr[o4];
                acc[o4*4+0] = fmaf(f, wv.x, acc[o4*4+0]);
                acc[o4*4+1] = fmaf(f, wv.y, acc[o4*4+1]);
                acc[o4*4+2] = fmaf(f, wv.z, acc[o4*4+2]);
                acc[o4*4+3] = fmaf(f, wv.w, acc[o4*4+3]);
            }
        }
        #pragma unroll
        for (int o = 0; o < 64; ++o) if (!valid) acc[o] = NEGINF;
        #pragma unroll
        for (int off = 16; off >= 1; off >>= 1) {
            #pragma unroll
            for (int o = 0; o < 64; ++o) acc[o] = fmaxf(acc[o], __shfl_xor(acc[o], off));
        }
        if (slot == 0) {
            #pragma unroll
            for (int o = 0; o < 64; o += 4) {
                float4 v = make_float4(acc[o], acc[o+1], acc[o+2], acc[o+3]);
                *(float4*)&orow[h*64+o] = v;
            }
        }
    }
}

// ------------------------------- launcher -----------------------------------
extern "C" void kernel_launch(void* const* d_in, const int* in_sizes, int n_in,
                              void* d_out, int out_size, void* d_ws, size_t ws_size,
                              hipStream_t stream) {
    const float* x   = (const float*)d_in[0];
    const float* pos = (const float*)d_in[1];
    // d_in[2]=batch (implicit), d_in[3]=num_samples (K=32 hardcoded)
    const float* W1 = (const float*)d_in[4];
    const float* b1 = (const float*)d_in[5];
    const float* W2 = (const float*)d_in[6];
    const float* b2 = (const float*)d_in[7];
    const float* W3 = (const float*)d_in[8];
    const float* b3 = (const float*)d_in[9];
    float* out = (float*)d_out;

    int* nidx = (int*)d_ws;                  // NQ*KK ints (2 MiB)
    int* ncnt = nidx + (size_t)NQ*KK;        // NQ ints

    hipLaunchKernelGGL(fps_kernel,    dim3(NB),      dim3(256), 0, stream, pos, out);
    hipLaunchKernelGGL(radius_kernel, dim3(NQ/16),   dim3(256), 0, stream, pos, out, nidx, ncnt);
    hipLaunchKernelGGL(mlp_kernel,    dim3(NQ/8),    dim3(256), 0, stream,
                       x, pos, W1, b1, W2, b2, W3, b3, nidx, ncnt, out);
}